// Round 1
// baseline (634.948 us; speedup 1.0000x reference)
//
#include <hip/hip_runtime.h>
#include <math.h>

#define EMBED 256
#define HEADS 8
#define LEVELS 4
#define POINTS 4
#define QN 21760          // Q == V == 21760
#define BS 2

// ---------------- tiled f32 GEMM: C = A(MxK) @ B(KxN) + bias(N) ----------------
#define BM 64
#define BN 64
#define BK 16

__global__ __launch_bounds__(256) void gemm_bias_f32(
    const float* __restrict__ A, const float* __restrict__ B,
    const float* __restrict__ bias, float* __restrict__ C,
    int M, int N, int K) {
  __shared__ float As[BK][BM + 4];   // +4 pad keeps 16B alignment for float4 reads
  __shared__ float Bs[BK][BN + 4];
  const int t  = threadIdx.x;
  const int bm = blockIdx.y * BM;
  const int bn = blockIdx.x * BN;
  const int ty = t >> 4, tx = t & 15;

  float acc[4][4];
#pragma unroll
  for (int i = 0; i < 4; ++i)
#pragma unroll
    for (int j = 0; j < 4; ++j) acc[i][j] = 0.f;

  for (int k0 = 0; k0 < K; k0 += BK) {
    // A tile: BM x BK (1024 elems, 4/thread), stored transposed As[k][m]
#pragma unroll
    for (int i = 0; i < 4; ++i) {
      int idx = t + i * 256;
      int r = idx >> 4;        // / BK
      int c = idx & 15;        // % BK
      As[c][r] = A[(size_t)(bm + r) * K + (k0 + c)];
    }
    // B tile: BK x BN
#pragma unroll
    for (int i = 0; i < 4; ++i) {
      int idx = t + i * 256;
      int r = idx >> 6;        // / BN
      int c = idx & 63;        // % BN
      Bs[r][c] = B[(size_t)(k0 + r) * N + (bn + c)];
    }
    __syncthreads();
#pragma unroll
    for (int kk = 0; kk < BK; ++kk) {
      float4 av = *(const float4*)&As[kk][ty * 4];
      float4 bv = *(const float4*)&Bs[kk][tx * 4];
      float a_[4] = {av.x, av.y, av.z, av.w};
      float b_[4] = {bv.x, bv.y, bv.z, bv.w};
#pragma unroll
      for (int i = 0; i < 4; ++i)
#pragma unroll
        for (int j = 0; j < 4; ++j) acc[i][j] += a_[i] * b_[j];
    }
    __syncthreads();
  }

#pragma unroll
  for (int i = 0; i < 4; ++i) {
    int row = bm + ty * 4 + i;
    int col = bn + tx * 4;
    float4 o;
    o.x = acc[i][0] + bias[col + 0];
    o.y = acc[i][1] + bias[col + 1];
    o.z = acc[i][2] + bias[col + 2];
    o.w = acc[i][3] + bias[col + 3];
    *(float4*)&C[(size_t)row * N + col] = o;
  }
}

// ---------------- deformable sampling ----------------
// one thread = one (b,q,h, 4-channel group); 8 threads cover d=32
__global__ __launch_bounds__(256) void msda_sample_f32(
    const float* __restrict__ val,     // (bs, V, 256)  value @ W_v + b_v
    const float* __restrict__ off,     // (bs, Q, 256)  query @ W_off + b_off
    const float* __restrict__ logits,  // (bs, Q, 128)  query @ W_attn + b_attn
    const float* __restrict__ ref,     // (bs, Q, 4, 2)
    float* __restrict__ interm) {      // (bs, Q, 256)
  const int lw[LEVELS]     = {128, 64, 32, 16};
  const int lh[LEVELS]     = {128, 64, 32, 16};
  const int lstart[LEVELS] = {0, 16384, 20480, 21504};

  int gid  = blockIdx.x * 256 + threadIdx.x;
  int sub  = gid & 7;          // channel group: c = sub*4
  int task = gid >> 3;
  int h    = task & 7;
  int bq   = task >> 3;        // b*Q + q
  int b    = (bq >= QN) ? 1 : 0;

  // softmax over the 16 (l,p) logits for this (b,q,h) — redundant per lane, cached
  const float* lg = logits + (size_t)bq * (HEADS * LEVELS * POINTS) + h * 16;
  float w[16];
  float m = -1e30f;
#pragma unroll
  for (int s = 0; s < 16; ++s) { w[s] = lg[s]; m = fmaxf(m, w[s]); }
  float sum = 0.f;
#pragma unroll
  for (int s = 0; s < 16; ++s) { w[s] = __expf(w[s] - m); sum += w[s]; }
  float inv = 1.f / sum;

  const float* offp  = off + (size_t)bq * 256 + h * 32;   // (l,p,xy): (l*4+p)*2+xy
  const float* refp  = ref + (size_t)bq * 8;              // (l,xy)
  const float* vbase = val + (size_t)b * QN * EMBED + h * 32 + sub * 4;

  float4 acc = {0.f, 0.f, 0.f, 0.f};
#pragma unroll
  for (int l = 0; l < LEVELS; ++l) {
    const float rx = refp[l * 2 + 0];
    const float ry = refp[l * 2 + 1];
    const int   W = lw[l], H = lh[l];
    const float fW = (float)W, fH = (float)H;
    const float* vl = vbase + (size_t)lstart[l] * EMBED;
#pragma unroll
    for (int p = 0; p < POINTS; ++p) {
      float ox = offp[(l * 4 + p) * 2 + 0];
      float oy = offp[(l * 4 + p) * 2 + 1];
      // loc = ref + off/norm;  x = loc*W - 0.5
      float x = rx * fW + ox - 0.5f;
      float y = ry * fH + oy - 0.5f;
      float x0f = floorf(x), y0f = floorf(y);
      int   x0 = (int)x0f,   y0 = (int)y0f;
      float fx = x - x0f,    fy = y - y0f;
      float a = w[l * 4 + p] * inv;
      float w00 = (1.f - fx) * (1.f - fy) * a;
      float w10 = fx * (1.f - fy) * a;
      float w01 = (1.f - fx) * fy * a;
      float w11 = fx * fy * a;
      bool xv0 = (x0 >= 0) && (x0 < W);
      bool xv1 = (x0 + 1 >= 0) && (x0 + 1 < W);
      bool yv0 = (y0 >= 0) && (y0 < H);
      bool yv1 = (y0 + 1 >= 0) && (y0 + 1 < H);
      if (yv0) {
        const float* row = vl + (size_t)y0 * W * EMBED;
        if (xv0) {
          float4 v = *(const float4*)(row + (size_t)x0 * EMBED);
          acc.x += w00 * v.x; acc.y += w00 * v.y; acc.z += w00 * v.z; acc.w += w00 * v.w;
        }
        if (xv1) {
          float4 v = *(const float4*)(row + (size_t)(x0 + 1) * EMBED);
          acc.x += w10 * v.x; acc.y += w10 * v.y; acc.z += w10 * v.z; acc.w += w10 * v.w;
        }
      }
      if (yv1) {
        const float* row = vl + (size_t)(y0 + 1) * W * EMBED;
        if (xv0) {
          float4 v = *(const float4*)(row + (size_t)x0 * EMBED);
          acc.x += w01 * v.x; acc.y += w01 * v.y; acc.z += w01 * v.z; acc.w += w01 * v.w;
        }
        if (xv1) {
          float4 v = *(const float4*)(row + (size_t)(x0 + 1) * EMBED);
          acc.x += w11 * v.x; acc.y += w11 * v.y; acc.z += w11 * v.z; acc.w += w11 * v.w;
        }
      }
    }
  }
  *(float4*)(interm + (size_t)bq * 256 + h * 32 + sub * 4) = acc;
}

extern "C" void kernel_launch(void* const* d_in, const int* in_sizes, int n_in,
                              void* d_out, int out_size, void* d_ws, size_t ws_size,
                              hipStream_t stream) {
  const float* query = (const float*)d_in[0];   // (2, 21760, 256)
  const float* value = (const float*)d_in[1];   // (2, 21760, 256)
  const float* ref   = (const float*)d_in[2];   // (2, 21760, 4, 2)
  // d_in[3] = spatial_shapes (static, hardcoded)
  const float* W_off  = (const float*)d_in[4];  // (256, 256)
  const float* b_off  = (const float*)d_in[5];  // (256,)
  const float* W_attn = (const float*)d_in[6];  // (256, 128)
  const float* b_attn = (const float*)d_in[7];  // (128,)
  const float* W_v    = (const float*)d_in[8];  // (256, 256)
  const float* b_v    = (const float*)d_in[9];  // (256,)
  const float* W_out  = (const float*)d_in[10]; // (256, 256)
  const float* b_out  = (const float*)d_in[11]; // (256,)
  float* out = (float*)d_out;                   // (2, 21760, 256)

  const int M = BS * QN;                        // 43520 rows (divisible by BM)
  const size_t szBQC = (size_t)M * EMBED;       // 11,141,120 floats

  // workspace layout
  float* ws_val    = (float*)d_ws;              // (bs,V,256)
  float* ws_off    = ws_val + szBQC;            // (bs,Q,256)
  float* ws_logits = ws_off + szBQC;            // (bs,Q,128)
  float* ws_interm = ws_logits + (size_t)M * 128; // (bs,Q,256)
  size_t need = (3 * szBQC + (size_t)M * 128) * sizeof(float);
  if (ws_size < need) return;  // insufficient scratch — fail loudly via wrong output

  dim3 blk(256);
  dim3 g256(EMBED / BN, M / BM);   // (4, 680)
  dim3 g128(128 / BN, M / BM);     // (2, 680)

  // 1) val = value @ W_v + b_v
  gemm_bias_f32<<<g256, blk, 0, stream>>>(value, W_v, b_v, ws_val, M, EMBED, EMBED);
  // 2) off = query @ W_off + b_off
  gemm_bias_f32<<<g256, blk, 0, stream>>>(query, W_off, b_off, ws_off, M, EMBED, EMBED);
  // 3) logits = query @ W_attn + b_attn
  gemm_bias_f32<<<g128, blk, 0, stream>>>(query, W_attn, b_attn, ws_logits, M, 128, EMBED);
  // 4) deformable sampling -> interm (bs,Q,256)
  int total = BS * QN * HEADS * 8;              // 2,785,280 threads
  msda_sample_f32<<<dim3(total / 256), blk, 0, stream>>>(ws_val, ws_off, ws_logits, ref, ws_interm);
  // 5) out = interm @ W_out + b_out
  gemm_bias_f32<<<g256, blk, 0, stream>>>(ws_interm, W_out, b_out, out, M, EMBED, EMBED);
}

// Round 2
// 310.995 us; speedup vs baseline: 2.0417x; 2.0417x over previous
//
#include <hip/hip_runtime.h>
#include <math.h>

#define EMBED 256
#define HEADS 8
#define LEVELS 4
#define POINTS 4
#define QN 21760          // Q == V == 21760
#define BS 2
#define MTOT (BS * QN)    // 43520, = 340 * 128

typedef __attribute__((ext_vector_type(8))) short bf16x8;
typedef __attribute__((ext_vector_type(4))) float f32x4;

__device__ inline ushort f2bf(float f) {
  union { float f; uint u; } v; v.f = f;
  uint r = (v.u + 0x7FFFu + ((v.u >> 16) & 1u)) >> 16;
  return (ushort)r;
}
__device__ inline float bflo(uint u) { union { uint u; float f; } v; v.u = u << 16; return v.f; }
__device__ inline float bfhi(uint u) { union { uint u; float f; } v; v.u = u & 0xFFFF0000u; return v.f; }
__device__ inline uint pk2(float lo, float hi) { return (uint)f2bf(lo) | ((uint)f2bf(hi) << 16); }

// -------- weight prep: W (K=256, N) f32  ->  Wt (N, 256) bf16 --------
__global__ __launch_bounds__(256) void prep_w(const float* __restrict__ W,
                                              ushort* __restrict__ Wt, int N) {
  int idx = blockIdx.x * 256 + threadIdx.x;  // over N*256
  int n = idx >> 8, k = idx & 255;
  Wt[idx] = f2bf(W[(size_t)k * N + n]);
}

// -------- MFMA bf16 GEMM: C = A(M,256) @ Wt(N,256)^T + bias --------
// MODE 0: f32 flat (M,N).  MODE 1: bf16 head-split (b*8+h, QN, 32), N must be 256.
// A_F32: A is f32 (cast fused into staging) else bf16.
template<int MODE, bool A_F32>
__global__ __launch_bounds__(256) void gemm_mfma(
    const void* __restrict__ A, const ushort* __restrict__ Bt,
    const float* __restrict__ bias, void* __restrict__ Cout, int N) {
  __shared__ ushort As[128][40];   // +8 pad (16B) keeps alignment, breaks bank stride
  __shared__ ushort Bs[128][40];
  const int t = threadIdx.x;
  const int wave = t >> 6, lane = t & 63;
  const int bm = blockIdx.y * 128, bn = blockIdx.x * 128;
  const int wm = (wave >> 1) * 64, wn = (wave & 1) * 64;
  const int l15 = lane & 15, l4 = lane >> 4;

  f32x4 acc[4][4];
#pragma unroll
  for (int i = 0; i < 4; ++i)
#pragma unroll
    for (int j = 0; j < 4; ++j) acc[i][j] = (f32x4){0.f, 0.f, 0.f, 0.f};

  for (int k0 = 0; k0 < 256; k0 += 32) {
    if (A_F32) {
      const float* Af = (const float*)A;
#pragma unroll
      for (int i = 0; i < 4; ++i) {
        int c = t + i * 256;
        int row = c >> 3, part = c & 7;
        float4 v = *(const float4*)&Af[(size_t)(bm + row) * 256 + k0 + part * 4];
        ushort4 hv; hv.x = f2bf(v.x); hv.y = f2bf(v.y); hv.z = f2bf(v.z); hv.w = f2bf(v.w);
        *(ushort4*)&As[row][part * 4] = hv;
      }
    } else {
      const ushort* Ah = (const ushort*)A;
#pragma unroll
      for (int i = 0; i < 2; ++i) {
        int c = t + i * 256;
        int row = c >> 2, part = c & 3;
        *(float4*)&As[row][part * 8] = *(const float4*)&Ah[(size_t)(bm + row) * 256 + k0 + part * 8];
      }
    }
#pragma unroll
    for (int i = 0; i < 2; ++i) {
      int c = t + i * 256;
      int row = c >> 2, part = c & 3;
      *(float4*)&Bs[row][part * 8] = *(const float4*)&Bt[(size_t)(bn + row) * 256 + k0 + part * 8];
    }
    __syncthreads();

    bf16x8 af[4], bfr[4];
#pragma unroll
    for (int mi = 0; mi < 4; ++mi) af[mi] = *(const bf16x8*)&As[wm + mi * 16 + l15][l4 * 8];
#pragma unroll
    for (int ni = 0; ni < 4; ++ni) bfr[ni] = *(const bf16x8*)&Bs[wn + ni * 16 + l15][l4 * 8];
#pragma unroll
    for (int mi = 0; mi < 4; ++mi)
#pragma unroll
      for (int ni = 0; ni < 4; ++ni)
        acc[mi][ni] = __builtin_amdgcn_mfma_f32_16x16x32_bf16(af[mi], bfr[ni], acc[mi][ni], 0, 0, 0);
    __syncthreads();
  }

#pragma unroll
  for (int mi = 0; mi < 4; ++mi) {
#pragma unroll
    for (int ni = 0; ni < 4; ++ni) {
      int col = bn + wn + ni * 16 + l15;
      float bv = bias[col];
#pragma unroll
      for (int r = 0; r < 4; ++r) {
        int row = bm + wm + mi * 16 + l4 * 4 + r;
        float v = acc[mi][ni][r] + bv;
        if (MODE == 0) {
          ((float*)Cout)[(size_t)row * N + col] = v;
        } else {
          int b = (row >= QN) ? 1 : 0;
          int vpos = row - b * QN;
          int h = col >> 5, c = col & 31;
          ((ushort*)Cout)[((size_t)(b * 8 + h) * QN + vpos) * 32 + c] = f2bf(v);
        }
      }
    }
  }
}

// -------- deformable sampling --------
// val: bf16 head-split (b*8+h, V, 32). h = blockIdx & 7 -> per-XCD L2 head locality.
// 4 sub-threads per (b,q,h), 8 channels each. Output interm bf16 flat (b,q,256).
__global__ __launch_bounds__(256) void msda_sample(
    const ushort* __restrict__ val, const float* __restrict__ off,
    const float* __restrict__ logits, const float* __restrict__ ref,
    ushort* __restrict__ interm) {
  const int lsz[LEVELS]    = {128, 64, 32, 16};
  const int lstart[LEVELS] = {0, 16384, 20480, 21504};

  int h   = blockIdx.x & 7;
  int z   = blockIdx.x >> 3;
  int sub = threadIdx.x & 3;
  int bq  = z * 64 + (threadIdx.x >> 2);    // 680*64 = 43520 exact
  int b   = (bq >= QN) ? 1 : 0;

  // softmax weights
  const float* lg = logits + (size_t)bq * 128 + h * 16;
  float w[16];
  float m = -1e30f;
#pragma unroll
  for (int s = 0; s < 16; ++s) { w[s] = lg[s]; m = fmaxf(m, w[s]); }
  float sum = 0.f;
#pragma unroll
  for (int s = 0; s < 16; ++s) { w[s] = __expf(w[s] - m); sum += w[s]; }
  float inv = 1.f / sum;

  float of[32];
  const float* offp = off + (size_t)bq * 256 + h * 32;
#pragma unroll
  for (int s = 0; s < 32; ++s) of[s] = offp[s];
  float rf[8];
  const float* refp = ref + (size_t)bq * 8;
#pragma unroll
  for (int s = 0; s < 8; ++s) rf[s] = refp[s];

  const ushort* vb = val + ((size_t)(b * 8 + h) * QN) * 32 + sub * 8;

  float acc[8] = {0.f, 0.f, 0.f, 0.f, 0.f, 0.f, 0.f, 0.f};

#pragma unroll
  for (int l = 0; l < LEVELS; ++l) {
    const int   W = lsz[l];
    const float fW = (float)W;
    const int   base = lstart[l];
    const float rx = rf[l * 2 + 0], ry = rf[l * 2 + 1];
#pragma unroll
    for (int p = 0; p < POINTS; ++p) {
      float x = rx * fW + of[l * 8 + p * 2 + 0] - 0.5f;
      float y = ry * fW + of[l * 8 + p * 2 + 1] - 0.5f;
      float x0f = floorf(x), y0f = floorf(y);
      int   x0 = (int)x0f,   y0 = (int)y0f;
      float fx = x - x0f,    fy = y - y0f;
      float a = w[l * 4 + p] * inv;
      float w00 = (1.f - fx) * (1.f - fy) * a;
      float w10 = fx * (1.f - fy) * a;
      float w01 = (1.f - fx) * fy * a;
      float w11 = fx * fy * a;
      bool xv0 = (x0 >= 0) && (x0 < W);
      bool xv1 = (x0 + 1 >= 0) && (x0 + 1 < W);
      bool yv0 = (y0 >= 0) && (y0 < W);
      bool yv1 = (y0 + 1 >= 0) && (y0 + 1 < W);

      const ushort* r0 = vb + (size_t)(base + y0 * W) * 32;
      const ushort* r1 = r0 + (size_t)W * 32;
      if (yv0 && xv0) {
        uint4 u = *(const uint4*)(r0 + (size_t)x0 * 32);
        acc[0] += w00 * bflo(u.x); acc[1] += w00 * bfhi(u.x);
        acc[2] += w00 * bflo(u.y); acc[3] += w00 * bfhi(u.y);
        acc[4] += w00 * bflo(u.z); acc[5] += w00 * bfhi(u.z);
        acc[6] += w00 * bflo(u.w); acc[7] += w00 * bfhi(u.w);
      }
      if (yv0 && xv1) {
        uint4 u = *(const uint4*)(r0 + (size_t)(x0 + 1) * 32);
        acc[0] += w10 * bflo(u.x); acc[1] += w10 * bfhi(u.x);
        acc[2] += w10 * bflo(u.y); acc[3] += w10 * bfhi(u.y);
        acc[4] += w10 * bflo(u.z); acc[5] += w10 * bfhi(u.z);
        acc[6] += w10 * bflo(u.w); acc[7] += w10 * bfhi(u.w);
      }
      if (yv1 && xv0) {
        uint4 u = *(const uint4*)(r1 + (size_t)x0 * 32);
        acc[0] += w01 * bflo(u.x); acc[1] += w01 * bfhi(u.x);
        acc[2] += w01 * bflo(u.y); acc[3] += w01 * bfhi(u.y);
        acc[4] += w01 * bflo(u.z); acc[5] += w01 * bfhi(u.z);
        acc[6] += w01 * bflo(u.w); acc[7] += w01 * bfhi(u.w);
      }
      if (yv1 && xv1) {
        uint4 u = *(const uint4*)(r1 + (size_t)(x0 + 1) * 32);
        acc[0] += w11 * bflo(u.x); acc[1] += w11 * bfhi(u.x);
        acc[2] += w11 * bflo(u.y); acc[3] += w11 * bfhi(u.y);
        acc[4] += w11 * bflo(u.z); acc[5] += w11 * bfhi(u.z);
        acc[6] += w11 * bflo(u.w); acc[7] += w11 * bfhi(u.w);
      }
    }
  }

  uint4 o;
  o.x = pk2(acc[0], acc[1]); o.y = pk2(acc[2], acc[3]);
  o.z = pk2(acc[4], acc[5]); o.w = pk2(acc[6], acc[7]);
  ushort* ip = interm + (size_t)bq * 256 + h * 32 + sub * 8;
  *(uint4*)ip = o;
}

extern "C" void kernel_launch(void* const* d_in, const int* in_sizes, int n_in,
                              void* d_out, int out_size, void* d_ws, size_t ws_size,
                              hipStream_t stream) {
  const float* query = (const float*)d_in[0];
  const float* value = (const float*)d_in[1];
  const float* ref   = (const float*)d_in[2];
  const float* W_off  = (const float*)d_in[4];
  const float* b_off  = (const float*)d_in[5];
  const float* W_attn = (const float*)d_in[6];
  const float* b_attn = (const float*)d_in[7];
  const float* W_v    = (const float*)d_in[8];
  const float* b_v    = (const float*)d_in[9];
  const float* W_out  = (const float*)d_in[10];
  const float* b_out  = (const float*)d_in[11];
  float* out = (float*)d_out;

  const size_t szBQC = (size_t)MTOT * EMBED;   // 11,141,120

  // workspace layout (all 16B aligned)
  ushort* ws_wv    = (ushort*)d_ws;                        // 65536
  ushort* ws_woff  = ws_wv + 65536;                        // 65536
  ushort* ws_wattn = ws_woff + 65536;                      // 32768
  ushort* ws_wout  = ws_wattn + 32768;                     // 65536
  ushort* ws_val   = ws_wout + 65536;                      // bf16 head-split (16, QN, 32)
  ushort* ws_interm= ws_val + szBQC;                       // bf16 flat (M,256)
  float*  ws_off   = (float*)(ws_interm + szBQC);          // f32 (M,256)
  float*  ws_log   = ws_off + szBQC;                       // f32 (M,128)
  size_t need = (size_t)(65536*3 + 32768) * 2 + 2 * szBQC * 2 + szBQC * 4 + (size_t)MTOT * 128 * 4;
  if (ws_size < need) return;

  dim3 blk(256);
  // weight prep (tiny)
  prep_w<<<dim3(256), blk, 0, stream>>>(W_v, ws_wv, 256);
  prep_w<<<dim3(256), blk, 0, stream>>>(W_off, ws_woff, 256);
  prep_w<<<dim3(128), blk, 0, stream>>>(W_attn, ws_wattn, 128);
  prep_w<<<dim3(256), blk, 0, stream>>>(W_out, ws_wout, 256);

  dim3 g256(2, MTOT / 128);
  dim3 g128(1, MTOT / 128);
  // val = value @ W_v + b_v  -> bf16 head-split
  gemm_mfma<1, true><<<g256, blk, 0, stream>>>(value, ws_wv, b_v, ws_val, 256);
  // off = query @ W_off + b_off -> f32
  gemm_mfma<0, true><<<g256, blk, 0, stream>>>(query, ws_woff, b_off, ws_off, 256);
  // logits = query @ W_attn + b_attn -> f32
  gemm_mfma<0, true><<<g128, blk, 0, stream>>>(query, ws_wattn, b_attn, ws_log, 128);
  // sampling -> interm bf16
  msda_sample<<<dim3(680 * 8), blk, 0, stream>>>(ws_val, ws_off, ws_log, ref, ws_interm);
  // out = interm @ W_out + b_out -> f32
  gemm_mfma<0, false><<<g256, blk, 0, stream>>>(ws_interm, ws_wout, b_out, out, 256);
}